// Round 13
// baseline (183.682 us; speedup 1.0000x reference)
//
#include <hip/hip_runtime.h>

#define NB     8192
#define HDIM   64
#define SEQ    180
#define MT     16     // batch rows per block
#define SB     72     // bf16 LDS row stride: 144 B, 16B-aligned (SB=68 regressed: misaligned b128)
#define XSP    100    // xs prologue row stride (floats)

typedef __bf16 bf16x8 __attribute__((ext_vector_type(8)));
typedef __bf16 bf16x4 __attribute__((ext_vector_type(4)));
typedef float  f32x4  __attribute__((ext_vector_type(4)));
typedef float  f32x2  __attribute__((ext_vector_type(2)));

#define L2E 1.44269504088896340736f

__device__ __forceinline__ float tanh_f(float x) {
    float e = __builtin_amdgcn_exp2f((2.0f * L2E) * x);
    return 1.0f - 2.0f * __builtin_amdgcn_rcpf(1.0f + e);
}

#define MFMA __builtin_amdgcn_mfma_f32_16x16x32_bf16

// In-loop barrier: LDS-only drain (R17: neutral vs __syncthreads; kept so the
// deferred head's global store floats across barriers).
#define BAR_LDS() asm volatile("s_waitcnt lgkmcnt(0)\n\ts_barrier" ::: "memory")

// R26 = R24 (best, 101us) + the two remaining register-neutral issue cuts:
//  (1) N-gate fold completed: w_hh_N pre-scaled by 2*L2E, C-seeded with
//      b_hhN*2L2E (REPLACES bn4 in the same 4 regs -- zero new constants;
//      R21's failure mode was extra live constants, not the scaling).
//      tN = fma(rg, aN, cN4): -4 muls.
//  (2) epilogue plain math rewritten as explicitly-threaded f32x2 halves
//      (lo/hi never recombined into f32x4) to force v_pk_{add,mul,fma}_f32
//      legalization if hipcc wasn't already packing -- 36 plain instr -> 18
//      if it wasn't. Trans ops (3 exp2 + 2 rcp per element) are scalar and
//      are the proven floor.
// Per-element scalar op ORDER is unchanged -> absmax must stay 0.00390625.
// R25 post-mortem: static asymmetric setprio neutral-to-negative; ALL
// cross-block phase tools now exhausted (sleep R15, toggled prio R20, split
// barriers R23, static prio R25). Only issue cuts pay (R18/R24: 2.7x
// issue->period multiplier). VGPR must stay <=128 (R21 cliff).
__global__ __launch_bounds__(256) void gru_all(
        const float* __restrict__ z, const int* __restrict__ labels,
        const float* __restrict__ embed_w, const float* __restrict__ fc_w,
        const float* __restrict__ fc_b, const float* __restrict__ w_hh,
        const float* __restrict__ b_ih, const float* __restrict__ b_hh,
        const float* __restrict__ out_w, const float* __restrict__ out_b,
        float* __restrict__ out) {
    __shared__ __align__(16) __bf16 hbuf[2][MT * SB];  // [buf] bf16(h)
    __shared__ __align__(16) float  xs[MT * XSP];      // h0 input [z|embed]

    const int t = threadIdx.x;
    const int w = t >> 6;          // wave 0..3
    const int l = t & 63;
    const int q = l >> 4;          // quad 0..3
    const int n16 = l & 15;
    const int jg = 16 * w + n16;   // W row this lane loads (A-frag m-index)
    const int jb = 16 * w + 4 * q; // first of the 4 h-cols this lane epilogues
    const int bbase = blockIdx.x * MT;

    // ---- prologue A: stage x = [z, embed(labels)] for 16 rows into LDS ----
    for (int c = t; c < MT * 24; c += 256) {    // 24 f32x4 chunks per row
        int m = c / 24, kk = (c % 24) * 4;
        f32x4 v;
        if (kk < 32) v = *(const f32x4*)(z + (size_t)(bbase + m) * 32 + kk);
        else         v = *(const f32x4*)(embed_w + labels[bbase + m] * 64 + (kk - 32));
        *(f32x4*)(xs + m * XSP + kk) = v;
    }

    // ---- persistent w_hh fragments: R,Z scaled by -L2E; N by +2*L2E ----
    // A[m = n16][k = q*8+j + 32ks] = scale[g] * w_hh[g*64 + jg][k]
    bf16x8 whi[3][2];
#pragma unroll
    for (int g = 0; g < 3; ++g) {
        const float wsc = (g == 2) ? (2.0f * L2E) : (-L2E);
        const float* pr = w_hh + (g * 64 + jg) * HDIM;
#pragma unroll
        for (int ks = 0; ks < 2; ++ks) {
            const float* p = pr + ks * 32 + q * 8;
            f32x4 va = *(const f32x4*)(p);
            f32x4 vb = *(const f32x4*)(p + 4);
#pragma unroll
            for (int j2 = 0; j2 < 4; ++j2) {
                whi[g][ks][j2]     = (__bf16)(va[j2] * wsc);
                whi[g][ks][4 + j2] = (__bf16)(vb[j2] * wsc);
            }
        }
    }

    // ---- output-head A fragments: A[m=n16][k] = out_w[n16][k] (n16<2 live) --
    bf16x8 obhi[2];
#pragma unroll
    for (int ks = 0; ks < 2; ++ks) {
        f32x4 va = {0.f, 0.f, 0.f, 0.f}, vb = {0.f, 0.f, 0.f, 0.f};
        if (n16 < 2) {
            va = *(const f32x4*)(out_w + n16 * 64 + ks * 32 + q * 8);
            vb = *(const f32x4*)(out_w + n16 * 64 + ks * 32 + q * 8 + 4);
        }
#pragma unroll
        for (int j2 = 0; j2 < 4; ++j2) {
            obhi[ks][j2]     = (__bf16)va[j2];
            obhi[ks][4 + j2] = (__bf16)vb[j2];
        }
    }
    // C/D bias by m-row (out-col): live rows m=0,1 sit at q==0, reg r=0,1
    const f32x4 obias = (q == 0) ? f32x4{out_b[0], out_b[1], 0.f, 0.f}
                                 : f32x4{0.f, 0.f, 0.f, 0.f};
    const f32x2 one2 = {1.f, 1.f};

    // every wave stores output for its 4 rows: q==0 lane, rows 4w..4w+3
    const bool ostorer = (q == 0) && ((n16 >> 2) == w);

    // per-lane gate constants over the lane's 4 cols jb..jb+3.
    // cR4/cZ4/bn4 are MFMA C-seeds; bn4 is now b_hhN*2L2E (same 4 regs).
    const f32x4 bihR = *(const f32x4*)(b_ih + jb);
    const f32x4 bhhR = *(const f32x4*)(b_hh + jb);
    const f32x4 bihZ = *(const f32x4*)(b_ih + 64 + jb);
    const f32x4 bhhZ = *(const f32x4*)(b_hh + 64 + jb);
    const f32x4 cR4 = (bihR + bhhR) * (-L2E);
    const f32x4 cZ4 = (bihZ + bhhZ) * (-L2E);
    const f32x4 bn4 = (*(const f32x4*)(b_hh + 128 + jb)) * (2.0f * L2E);
    const f32x4 cN4f = (*(const f32x4*)(b_ih + 128 + jb)) * (2.0f * L2E);
    const f32x2 cN4l = {cN4f[0], cN4f[1]};
    const f32x2 cN4h = {cN4f[2], cN4f[3]};

    const int rdoff = n16 * SB + q * 8;    // h B-frag offset (16B-aligned)
    const int wboff = n16 * SB + jb;       // state-write offset (8B-aligned)
    float* opb = out + (size_t)(bbase + n16) * (SEQ * 2);  // this lane's row

    __syncthreads();   // xs ready

    // ---- prologue B: h0 = tanh(fc_b + fc_w . x); lane -> row n16, 4 cols ----
    f32x2 hpl, hph;    // fp32 carry, threaded as lo/hi halves
    {
        f32x4 a = *(const f32x4*)(fc_b + jb);
        for (int kc = 0; kc < 24; ++kc) {
            f32x4 xv = *(const f32x4*)(xs + n16 * XSP + kc * 4);
#pragma unroll
            for (int r = 0; r < 4; ++r) {
                f32x4 wv = *(const f32x4*)(fc_w + (size_t)(jb + r) * 96 + kc * 4);
                a[r] += wv[0] * xv[0] + wv[1] * xv[1] + wv[2] * xv[2] + wv[3] * xv[3];
            }
        }
        float t0 = tanh_f(a[0]), t1 = tanh_f(a[1]);
        float t2 = tanh_f(a[2]), t3 = tanh_f(a[3]);
        hpl = f32x2{t0, t1};
        hph = f32x2{t2, t3};
        bf16x4 hp;
        hp[0] = (__bf16)t0; hp[1] = (__bf16)t1;
        hp[2] = (__bf16)t2; hp[3] = (__bf16)t3;
        *(bf16x4*)(hbuf[0] + wboff) = hp;   // one ds_write_b64
    }
    __syncthreads();   // state 0 published in buf 0

    // Anti-phase the two co-resident blocks (i and i+256 share a CU).
    if ((blockIdx.x >> 8) & 1) __builtin_amdgcn_s_sleep(11);

    // previous step's b-frags for the deferred head (garbage first 2 iters;
    // computed unconditionally for wave balance, store is predicated)
    bf16x8 pb0 = {}, pb1 = {};

    for (int u = 0; u < SEQ / 4; ++u) {
#pragma unroll
        for (int s = 0; s < 4; ++s) {
            const int p = s & 1;
            const __bf16* Hh = hbuf[p];
            __bf16* Nh = hbuf[1 - p];

            // h B-frags of state i = 4u+s: B[k=q*8+j][n16] = h[n16][k]
            bf16x8 b0 = *(const bf16x8*)(Hh + rdoff);
            bf16x8 b1 = *(const bf16x8*)(Hh + rdoff + 32);

            // deferred output head (state i-1 -> out row i-2): register-only
            // MFMAs fill the ds_read lgkm-wait shadow right after the barrier
            {
                f32x4 o = obias;
                o = MFMA(obhi[0], pb0, o, 0, 0, 0);
                o = MFMA(obhi[1], pb1, o, 0, 0, 0);
                if ((u > 0 || s >= 2) && ostorer)
                    *(float2*)(opb + (8 * u + 2 * s - 4)) = make_float2(o[0], o[1]);
            }

            __builtin_amdgcn_s_setprio(1);

            // gates, bias-seeded & fully pre-scaled:
            // aR = -L2E*(W_R.h + bR_tot), aZ = -L2E*(W_Z.h + bZ_tot),
            // aN = 2L2E*(W_N.h + b_hhN)
            f32x4 aR, aZ, aN;
            aR = MFMA(whi[0][0], b0, cR4, 0, 0, 0);
            aZ = MFMA(whi[1][0], b0, cZ4, 0, 0, 0);
            aN = MFMA(whi[2][0], b0, bn4, 0, 0, 0);
            aR = MFMA(whi[0][1], b1, aR, 0, 0, 0);
            aZ = MFMA(whi[1][1], b1, aZ, 0, 0, 0);
            aN = MFMA(whi[2][1], b1, aN, 0, 0, 0);

            // fused epilogue, plain math in explicit f32x2 halves (v_pk_*):
            // h' = [h*(eN+1) + eZ*(eN-1)] / [(eN+1)(1+eZ)]
            f32x2 eRl, eRh, eZl, eZh;
            eRl[0] = __builtin_amdgcn_exp2f(aR[0]);
            eRl[1] = __builtin_amdgcn_exp2f(aR[1]);
            eRh[0] = __builtin_amdgcn_exp2f(aR[2]);
            eRh[1] = __builtin_amdgcn_exp2f(aR[3]);
            eZl[0] = __builtin_amdgcn_exp2f(aZ[0]);
            eZl[1] = __builtin_amdgcn_exp2f(aZ[1]);
            eZh[0] = __builtin_amdgcn_exp2f(aZ[2]);
            eZh[1] = __builtin_amdgcn_exp2f(aZ[3]);
            f32x2 Al = eRl + one2, Ah = eRh + one2;
            f32x2 rgl, rgh;
            rgl[0] = __builtin_amdgcn_rcpf(Al[0]);
            rgl[1] = __builtin_amdgcn_rcpf(Al[1]);
            rgh[0] = __builtin_amdgcn_rcpf(Ah[0]);
            rgh[1] = __builtin_amdgcn_rcpf(Ah[1]);
            f32x2 aNl = {aN[0], aN[1]}, aNh = {aN[2], aN[3]};
            f32x2 tNl = rgl * aNl + cN4l;    // aN already 2L2E*(n-preact)
            f32x2 tNh = rgh * aNh + cN4h;
            f32x2 eNl, eNh;
            eNl[0] = __builtin_amdgcn_exp2f(tNl[0]);
            eNl[1] = __builtin_amdgcn_exp2f(tNl[1]);
            eNh[0] = __builtin_amdgcn_exp2f(tNh[0]);
            eNh[1] = __builtin_amdgcn_exp2f(tNh[1]);
            f32x2 wzl = eZl + one2, wzh = eZh + one2;   // 1 + eZ
            f32x2 pzl = eZl + hpl,  pzh = eZh + hph;    // eZ + h
            f32x2 qzl = hpl - eZl,  qzh = hph - eZh;    // h - eZ
            f32x2 Nsl = eNl * pzl + qzl, Nsh = eNh * pzh + qzh;
            f32x2 Dsl = eNl * wzl + wzl, Dsh = eNh * wzh + wzh;
            f32x2 rDl, rDh;
            rDl[0] = __builtin_amdgcn_rcpf(Dsl[0]);
            rDl[1] = __builtin_amdgcn_rcpf(Dsl[1]);
            rDh[0] = __builtin_amdgcn_rcpf(Dsh[0]);
            rDh[1] = __builtin_amdgcn_rcpf(Dsh[1]);
            f32x2 hnl = Nsl * rDl, hnh = Nsh * rDh;     // exact fp32 carry
            hpl = hnl; hph = hnh;
            bf16x4 hp;
            hp[0] = (__bf16)hnl[0]; hp[1] = (__bf16)hnl[1];
            hp[2] = (__bf16)hnh[0]; hp[3] = (__bf16)hnh[1];
            *(bf16x4*)(Nh + wboff) = hp;     // one ds_write_b64

            __builtin_amdgcn_s_setprio(0);

            pb0 = b0; pb1 = b1;              // renamed, not copied (unroll 4)

            BAR_LDS();   // state i+1 published (LDS-only drain; stores float)
        }
    }

    // tail: deferred head of state 179 (pb) -> row 178, then state 180 -> 179
    {
        f32x4 o = obias;
        o = MFMA(obhi[0], pb0, o, 0, 0, 0);
        o = MFMA(obhi[1], pb1, o, 0, 0, 0);
        if (ostorer)
            *(float2*)(opb + (SEQ - 2) * 2) = make_float2(o[0], o[1]);

        const __bf16* Hh = hbuf[0];
        bf16x8 b0 = *(const bf16x8*)(Hh + rdoff);
        bf16x8 b1 = *(const bf16x8*)(Hh + rdoff + 32);
        f32x4 o2 = obias;
        o2 = MFMA(obhi[0], b0, o2, 0, 0, 0);
        o2 = MFMA(obhi[1], b1, o2, 0, 0, 0);
        if (ostorer)
            *(float2*)(opb + (SEQ - 1) * 2) = make_float2(o2[0], o2[1]);
    }
}

extern "C" void kernel_launch(void* const* d_in, const int* in_sizes, int n_in,
                              void* d_out, int out_size, void* d_ws, size_t ws_size,
                              hipStream_t stream) {
    (void)in_sizes; (void)n_in; (void)out_size; (void)d_ws; (void)ws_size;
    const float* z       = (const float*)d_in[0];
    const int*   labels  = (const int*)d_in[1];
    const float* embed_w = (const float*)d_in[2];
    const float* fc_w    = (const float*)d_in[3];
    const float* fc_b    = (const float*)d_in[4];
    // d_in[5] = w_ih: unused (GRU input is all zeros; b_ih carries the effect)
    const float* w_hh    = (const float*)d_in[6];
    const float* b_ih    = (const float*)d_in[7];
    const float* b_hh    = (const float*)d_in[8];
    const float* out_w   = (const float*)d_in[9];
    const float* out_b   = (const float*)d_in[10];
    float* out = (float*)d_out;

    gru_all<<<NB / MT, 256, 0, stream>>>(z, labels, embed_w, fc_w, fc_b,
                                         w_hh, b_ih, b_hh, out_w, out_b, out);
}